// Round 4
// baseline (6883.083 us; speedup 1.0000x reference)
//
#include <hip/hip_runtime.h>
#include <hip/hip_bf16.h>

// NeuralODE: B=256, Z=1024, H=2048, T=128, explicit Euler, 127 steps.
// Round 3: R2 design with the atomic-alignment fix — cross-WG exchange
// buffers are native ull arrays (8B-aligned), indexed in 8B units.
// Cross-WG data goes through L3 via RELAXED agent-scope atomics (no cache
// maintenance) -> per-XCD L2 never invalidated -> weight slices stay
// L2-resident across all 127 steps. Producer publishes a RELEASE fetch_add
// flag after __syncthreads (vmcnt(0) drain => data visible at L3 first);
// consumers poll with RELAXED loads. fp32 z-state lives in registers.

#define ZD 1024
#define HD 2048
#define TT 128
#define BB 256
#define ZT (ZD * TT)

typedef __attribute__((ext_vector_type(8))) short bfrag;  // 8 bf16
typedef __attribute__((ext_vector_type(4))) float ffrag;  // 4 fp32
typedef unsigned long long ull;

__device__ short g_W1b[HD * ZD];       // 4 MB bf16, [h][z]
__device__ short g_W2b[ZD * HD];       // 4 MB bf16, [z][h]
__device__ ull g_zbx[BB * ZD / 4];     // bf16 z exchange, 8B chunks
__device__ ull g_hbx[BB * HD / 4];     // bf16 h exchange, 8B chunks
__device__ unsigned g_cnt[64];         // [mg]=z gen, [16+mg]=h gen

__device__ __forceinline__ short f2bf(float f) {
  union { float f; unsigned u; } x; x.f = f;
  unsigned r = x.u + 0x7fffu + ((x.u >> 16) & 1u);  // RNE
  return (short)(r >> 16);
}

// XOR-swizzle of 16B blocks within an LDS row (kills stride bank conflicts).
__device__ __forceinline__ int swzA(int row, int k) {  // 1024-wide rows
  return (row << 10) + ((((k >> 3) ^ row) << 3) | (k & 7));
}
__device__ __forceinline__ int swzH(int row, int k) {  // 2048-wide rows
  return (row << 11) + ((((k >> 3) ^ row) << 3) | (k & 7));
}

__global__ void zero_cnt_kernel() {
  if (threadIdx.x < 64) g_cnt[threadIdx.x] = 0u;
}

__global__ void cvt_weights_kernel(const float* __restrict__ W1,
                                   const float* __restrict__ W2) {
  const int i = (blockIdx.x * 256 + threadIdx.x) << 2;
  {
    const float4 v = *(const float4*)(W1 + i);
    short4 o; o.x = f2bf(v.x); o.y = f2bf(v.y); o.z = f2bf(v.z); o.w = f2bf(v.w);
    *(short4*)(g_W1b + i) = o;
  }
  {
    const float4 v = *(const float4*)(W2 + i);
    short4 o; o.x = f2bf(v.x); o.y = f2bf(v.y); o.z = f2bf(v.z); o.w = f2bf(v.w);
    *(short4*)(g_W2b + i) = o;
  }
}

__global__ __launch_bounds__(512, 2) void ode_main(
    const float* __restrict__ z0, const float* __restrict__ ts,
    const float* __restrict__ wt, const float* __restrict__ b1,
    const float* __restrict__ b2, float* __restrict__ out) {
  __shared__ short buf[32 * 1024];        // 64 KB, time-shared
  short* const hloc = buf + 16384;        // 16 rows x stride 132 (after GEMM1)
  short* const zloc = buf + 8192;         // 16 rows x stride 68 (after GEMM2)
  float* const red = (float*)buf;         // 4 KB K-split reduction (after GEMM2)

  const int tid = threadIdx.x;
  const int wv = tid >> 6, lane = tid & 63, l16 = lane & 15, quad = lane >> 4;
  const int b = blockIdx.x;
  const int ng = ((b & 7) << 1) | ((b >> 3) & 1);  // same-ng -> same XCD
  const int mg = b >> 4;
  const int r0 = mg << 4;
  const int nq = wv & 3, kh = wv >> 2;
  const int zc0 = (ng << 6) + (nq << 4);

  float zreg[4];  // fp32 z state, valid in kh==0 waves

  // ---- init: z0 -> registers, out[t=0], publish bf16 z ----
  if (kh == 0) {
#pragma unroll
    for (int rg = 0; rg < 4; ++rg) {
      const int row = (quad << 2) + rg;
      zreg[rg] = z0[(r0 + row) * ZD + zc0 + l16];
      out[(size_t)(r0 + row) * ZT + (size_t)(zc0 + l16) * TT] = zreg[rg];
      zloc[row * 68 + (nq << 4) + l16] = f2bf(zreg[rg]);
    }
  }
  __syncthreads();
  if (tid < 256) {
    const int row = tid >> 4, ch = (tid & 15) << 2;  // ch: bf16 offset, mult of 4
    const ull v = *(const ull*)(zloc + row * 68 + ch);
    __hip_atomic_store(&g_zbx[((r0 + row) * ZD + (ng << 6) + ch) >> 2], v,
                       __ATOMIC_RELAXED, __HIP_MEMORY_SCOPE_AGENT);
  }
  __syncthreads();  // drains vmcnt: all publishes at L3
  if (tid == 0)
    __hip_atomic_fetch_add(&g_cnt[mg], 1u, __ATOMIC_RELEASE,
                           __HIP_MEMORY_SCOPE_AGENT);

#pragma unroll 1
  for (int t = 0; t < TT - 1; ++t) {
    const float tv = ts[t];
    const float dtv = ts[t + 1] - tv;

    // ---- wait: z generation t complete (relaxed poll, no L2 invalidate) ----
    if (tid == 0) {
      const unsigned tgt = 16u * (unsigned)(t + 1);
      while (__hip_atomic_load(&g_cnt[mg], __ATOMIC_RELAXED,
                               __HIP_MEMORY_SCOPE_AGENT) < tgt)
        __builtin_amdgcn_s_sleep(1);
    }
    __syncthreads();

    // ---- stage z (16x1024 bf16) from L3 into LDS, swizzled ----
#pragma unroll
    for (int i = 0; i < 8; ++i) {
      const int e = tid + (i << 9);
      const int r = e >> 8, k = (e & 255) << 2;
      const ull v = __hip_atomic_load(&g_zbx[((r0 + r) * ZD + k) >> 2],
                                      __ATOMIC_RELAXED, __HIP_MEMORY_SCOPE_AGENT);
      *(ull*)(buf + swzA(r, k)) = v;
    }
    __syncthreads();

    // ---- GEMM1: h rows [r0,+16) cols [hc0,+16), K=1024, W1 from L2 ----
    const int hc0 = (ng << 7) + (wv << 4);
    ffrag accA = {0.f, 0.f, 0.f, 0.f};
#pragma unroll 8
    for (int kk = 0; kk < 32; ++kk) {
      const int k0 = (kk << 5) + (quad << 3);
      const bfrag a = *(const bfrag*)(buf + swzA(l16, k0));
      const bfrag bm = *(const bfrag*)(g_W1b + (size_t)(hc0 + l16) * ZD + k0);
      accA = __builtin_amdgcn_mfma_f32_16x16x32_bf16(a, bm, accA, 0, 0, 0);
    }
    {
      const int hc = hc0 + l16;
      const float wtv = wt[hc], b1v = b1[hc];
      const int cl = (wv << 4) + l16;
#pragma unroll
      for (int rg = 0; rg < 4; ++rg)
        hloc[((quad << 2) + rg) * 132 + cl] =
            f2bf(tanhf(accA[rg] + tv * wtv + b1v));
    }
    __syncthreads();

    // ---- publish h slice (16x128) as 8B chunks ----
    {
      const int row = tid >> 5, ch = (tid & 31) << 2;
      const ull v = *(const ull*)(hloc + row * 132 + ch);
      __hip_atomic_store(&g_hbx[((r0 + row) * HD + (ng << 7) + ch) >> 2], v,
                         __ATOMIC_RELAXED, __HIP_MEMORY_SCOPE_AGENT);
    }
    __syncthreads();  // drain: h at L3
    if (tid == 0)
      __hip_atomic_fetch_add(&g_cnt[16 + mg], 1u, __ATOMIC_RELEASE,
                             __HIP_MEMORY_SCOPE_AGENT);

    // ---- wait: h generation t complete ----
    if (tid == 0) {
      const unsigned tgt = 16u * (unsigned)(t + 1);
      while (__hip_atomic_load(&g_cnt[16 + mg], __ATOMIC_RELAXED,
                               __HIP_MEMORY_SCOPE_AGENT) < tgt)
        __builtin_amdgcn_s_sleep(1);
    }
    __syncthreads();

    // ---- stage h (16x2048 bf16 = 64 KB) from L3 into LDS, swizzled ----
#pragma unroll
    for (int i = 0; i < 16; ++i) {
      const int e = tid + (i << 9);
      const int r = e >> 9, k = (e & 511) << 2;
      const ull v = __hip_atomic_load(&g_hbx[((r0 + r) * HD + k) >> 2],
                                      __ATOMIC_RELAXED, __HIP_MEMORY_SCOPE_AGENT);
      *(ull*)(buf + swzH(r, k)) = v;
    }
    __syncthreads();

    // ---- GEMM2 (2-way K-split across wave pairs), W2 from L2 ----
    ffrag accB = {0.f, 0.f, 0.f, 0.f};
#pragma unroll 8
    for (int kk = 0; kk < 32; ++kk) {
      const int k0 = (kh << 10) + (kk << 5) + (quad << 3);
      const bfrag a = *(const bfrag*)(buf + swzH(l16, k0));
      const bfrag bm = *(const bfrag*)(g_W2b + (size_t)(zc0 + l16) * HD + k0);
      accB = __builtin_amdgcn_mfma_f32_16x16x32_bf16(a, bm, accB, 0, 0, 0);
    }
    __syncthreads();  // all buf reads done
    if (kh == 1) *(ffrag*)(red + (((nq << 6) + lane) << 2)) = accB;
    __syncthreads();
    if (kh == 0) {
      accB += *(const ffrag*)(red + (((nq << 6) + lane) << 2));
      const int zc = zc0 + l16;
      const float b2v = b2[zc];
#pragma unroll
      for (int rg = 0; rg < 4; ++rg) {
        const int row = (quad << 2) + rg;
        zreg[rg] += dtv * (accB[rg] + b2v);
        out[(size_t)(r0 + row) * ZT + (size_t)zc * TT + t + 1] = zreg[rg];
        zloc[row * 68 + (nq << 4) + l16] = f2bf(zreg[rg]);
      }
    }
    __syncthreads();

    // ---- publish z slice (16x64) as 8B chunks ----
    if (tid < 256) {
      const int row = tid >> 4, ch = (tid & 15) << 2;
      const ull v = *(const ull*)(zloc + row * 68 + ch);
      __hip_atomic_store(&g_zbx[((r0 + row) * ZD + (ng << 6) + ch) >> 2], v,
                         __ATOMIC_RELAXED, __HIP_MEMORY_SCOPE_AGENT);
    }
    __syncthreads();  // drain: z at L3
    if (tid == 0)
      __hip_atomic_fetch_add(&g_cnt[mg], 1u, __ATOMIC_RELEASE,
                             __HIP_MEMORY_SCOPE_AGENT);
  }
}

extern "C" void kernel_launch(void* const* d_in, const int* in_sizes, int n_in,
                              void* d_out, int out_size, void* d_ws, size_t ws_size,
                              hipStream_t stream) {
  const float* z0 = (const float*)d_in[0];
  const float* ts = (const float*)d_in[1];
  const float* W1 = (const float*)d_in[2];
  const float* wt = (const float*)d_in[3];
  const float* b1 = (const float*)d_in[4];
  const float* W2 = (const float*)d_in[5];
  const float* b2 = (const float*)d_in[6];
  float* out = (float*)d_out;

  zero_cnt_kernel<<<1, 64, 0, stream>>>();
  cvt_weights_kernel<<<(HD * ZD) / 1024, 256, 0, stream>>>(W1, W2);
  ode_main<<<256, 512, 0, stream>>>(z0, ts, wt, b1, b2, out);
}

// Round 5
// 3917.214 us; speedup vs baseline: 1.7571x; 1.7571x over previous
//
#include <hip/hip_runtime.h>
#include <hip/hip_bf16.h>

// NeuralODE: B=256, Z=1024, H=2048, T=128, explicit Euler, 127 steps.
// Round 4: R3 data path, but ZERO cache-maintenance sync. No release/acquire
// anywhere in the loop (agent-scope release RMW emits buffer_wbl2 = full L2
// dirty walk -> suspected 27us/phase serializer). Producers publish per-WG
// PADDED flag slots with plain RELAXED atomic stores (no RMW); __syncthreads'
// vmcnt(0) drain orders the sc1 data stores before the flag store. Consumers
// poll 16 flags in parallel (wave 0, lane-per-flag, __all ballot).

#define ZD 1024
#define HD 2048
#define TT 128
#define BB 256
#define ZT (ZD * TT)

typedef __attribute__((ext_vector_type(8))) short bfrag;  // 8 bf16
typedef __attribute__((ext_vector_type(4))) float ffrag;  // 4 fp32
typedef unsigned long long ull;

__device__ short g_W1b[HD * ZD];       // 4 MB bf16, [h][z]
__device__ short g_W2b[ZD * HD];       // 4 MB bf16, [z][h]
__device__ ull g_zbx[BB * ZD / 4];     // bf16 z exchange, 8B chunks
__device__ ull g_hbx[BB * HD / 4];     // bf16 h exchange, 8B chunks
__device__ unsigned g_zfl[16 * 16 * 32];  // per-(mg,ng) z flag, 128B padded
__device__ unsigned g_hfl[16 * 16 * 32];  // per-(mg,ng) h flag, 128B padded

__device__ __forceinline__ short f2bf(float f) {
  union { float f; unsigned u; } x; x.f = f;
  unsigned r = x.u + 0x7fffu + ((x.u >> 16) & 1u);  // RNE
  return (short)(r >> 16);
}

// XOR-swizzle of 16B blocks within an LDS row (kills stride bank conflicts).
__device__ __forceinline__ int swzA(int row, int k) {  // 1024-wide rows
  return (row << 10) + ((((k >> 3) ^ row) << 3) | (k & 7));
}
__device__ __forceinline__ int swzH(int row, int k) {  // 2048-wide rows
  return (row << 11) + ((((k >> 3) ^ row) << 3) | (k & 7));
}

__global__ void zero_flags_kernel() {
  const int i = blockIdx.x * 1024 + threadIdx.x;
  __hip_atomic_store(&g_zfl[i], 0u, __ATOMIC_RELAXED, __HIP_MEMORY_SCOPE_AGENT);
  __hip_atomic_store(&g_hfl[i], 0u, __ATOMIC_RELAXED, __HIP_MEMORY_SCOPE_AGENT);
}

__global__ void cvt_weights_kernel(const float* __restrict__ W1,
                                   const float* __restrict__ W2) {
  const int i = (blockIdx.x * 256 + threadIdx.x) << 2;
  {
    const float4 v = *(const float4*)(W1 + i);
    short4 o; o.x = f2bf(v.x); o.y = f2bf(v.y); o.z = f2bf(v.z); o.w = f2bf(v.w);
    *(short4*)(g_W1b + i) = o;
  }
  {
    const float4 v = *(const float4*)(W2 + i);
    short4 o; o.x = f2bf(v.x); o.y = f2bf(v.y); o.z = f2bf(v.z); o.w = f2bf(v.w);
    *(short4*)(g_W2b + i) = o;
  }
}

__global__ __launch_bounds__(512, 2) void ode_main(
    const float* __restrict__ z0, const float* __restrict__ ts,
    const float* __restrict__ wt, const float* __restrict__ b1,
    const float* __restrict__ b2, float* __restrict__ out) {
  __shared__ short buf[32 * 1024];        // 64 KB, time-shared
  short* const hloc = buf + 16384;        // 16 rows x stride 132 (after GEMM1)
  short* const zloc = buf + 8192;         // 16 rows x stride 68 (after GEMM2)
  float* const red = (float*)buf;         // 4 KB K-split reduction (after GEMM2)

  const int tid = threadIdx.x;
  const int wv = tid >> 6, lane = tid & 63, l16 = lane & 15, quad = lane >> 4;
  const int b = blockIdx.x;
  const int ng = ((b & 7) << 1) | ((b >> 3) & 1);  // same-ng -> same XCD
  const int mg = b >> 4;
  const int r0 = mg << 4;
  const int nq = wv & 3, kh = wv >> 2;
  const int zc0 = (ng << 6) + (nq << 4);
  const int myslot = ((mg << 4) + ng) << 5;        // my padded flag index
  const int pollslot = ((mg << 4) + l16) << 5;     // wave-0 poll index

  float zreg[4];  // fp32 z state, valid in kh==0 waves

  // ---- init: z0 -> registers, out[t=0], publish bf16 z(0) ----
  if (kh == 0) {
#pragma unroll
    for (int rg = 0; rg < 4; ++rg) {
      const int row = (quad << 2) + rg;
      zreg[rg] = z0[(r0 + row) * ZD + zc0 + l16];
      out[(size_t)(r0 + row) * ZT + (size_t)(zc0 + l16) * TT] = zreg[rg];
      zloc[row * 68 + (nq << 4) + l16] = f2bf(zreg[rg]);
    }
  }
  __syncthreads();
  if (tid < 256) {
    const int row = tid >> 4, ch = (tid & 15) << 2;
    const ull v = *(const ull*)(zloc + row * 68 + ch);
    __hip_atomic_store(&g_zbx[((r0 + row) * ZD + (ng << 6) + ch) >> 2], v,
                       __ATOMIC_RELAXED, __HIP_MEMORY_SCOPE_AGENT);
  }
  __syncthreads();  // vmcnt(0): z(0) chunks at coherence point
  if (tid == 0)
    __hip_atomic_store(&g_zfl[myslot], 1u, __ATOMIC_RELAXED,
                       __HIP_MEMORY_SCOPE_AGENT);

#pragma unroll 1
  for (int t = 0; t < TT - 1; ++t) {
    const float tv = ts[t];
    const float dtv = ts[t + 1] - tv;

    // ---- wait: z(t) published by all 16 group members ----
    if (wv == 0) {
      const unsigned tgt = (unsigned)(t + 1);
      while (true) {
        const unsigned f = __hip_atomic_load(&g_zfl[pollslot], __ATOMIC_RELAXED,
                                             __HIP_MEMORY_SCOPE_AGENT);
        if (__all(f >= tgt)) break;
        __builtin_amdgcn_s_sleep(2);
      }
    }
    __syncthreads();

    // ---- stage z (16x1024 bf16) into LDS, swizzled ----
#pragma unroll
    for (int i = 0; i < 8; ++i) {
      const int e = tid + (i << 9);
      const int r = e >> 8, k = (e & 255) << 2;
      const ull v = __hip_atomic_load(&g_zbx[((r0 + r) * ZD + k) >> 2],
                                      __ATOMIC_RELAXED, __HIP_MEMORY_SCOPE_AGENT);
      *(ull*)(buf + swzA(r, k)) = v;
    }
    __syncthreads();

    // ---- GEMM1: h rows [r0,+16) cols [hc0,+16), K=1024, W1 from L2 ----
    const int hc0 = (ng << 7) + (wv << 4);
    ffrag accA = {0.f, 0.f, 0.f, 0.f};
#pragma unroll 8
    for (int kk = 0; kk < 32; ++kk) {
      const int k0 = (kk << 5) + (quad << 3);
      const bfrag a = *(const bfrag*)(buf + swzA(l16, k0));
      const bfrag bm = *(const bfrag*)(g_W1b + (size_t)(hc0 + l16) * ZD + k0);
      accA = __builtin_amdgcn_mfma_f32_16x16x32_bf16(a, bm, accA, 0, 0, 0);
    }
    {
      const int hc = hc0 + l16;
      const float wtv = wt[hc], b1v = b1[hc];
      const int cl = (wv << 4) + l16;
#pragma unroll
      for (int rg = 0; rg < 4; ++rg)
        hloc[((quad << 2) + rg) * 132 + cl] =
            f2bf(tanhf(accA[rg] + tv * wtv + b1v));
    }
    __syncthreads();

    // ---- publish h slice (16x128) as 8B chunks ----
    {
      const int row = tid >> 5, ch = (tid & 31) << 2;
      const ull v = *(const ull*)(hloc + row * 132 + ch);
      __hip_atomic_store(&g_hbx[((r0 + row) * HD + (ng << 7) + ch) >> 2], v,
                         __ATOMIC_RELAXED, __HIP_MEMORY_SCOPE_AGENT);
    }
    __syncthreads();  // vmcnt(0): h(t) at coherence point
    if (tid == 0)
      __hip_atomic_store(&g_hfl[myslot], (unsigned)(t + 1), __ATOMIC_RELAXED,
                         __HIP_MEMORY_SCOPE_AGENT);

    // ---- wait: h(t) published by all 16 group members ----
    if (wv == 0) {
      const unsigned tgt = (unsigned)(t + 1);
      while (true) {
        const unsigned f = __hip_atomic_load(&g_hfl[pollslot], __ATOMIC_RELAXED,
                                             __HIP_MEMORY_SCOPE_AGENT);
        if (__all(f >= tgt)) break;
        __builtin_amdgcn_s_sleep(2);
      }
    }
    __syncthreads();

    // ---- stage h (16x2048 bf16 = 64 KB) into LDS, swizzled ----
#pragma unroll
    for (int i = 0; i < 16; ++i) {
      const int e = tid + (i << 9);
      const int r = e >> 9, k = (e & 511) << 2;
      const ull v = __hip_atomic_load(&g_hbx[((r0 + r) * HD + k) >> 2],
                                      __ATOMIC_RELAXED, __HIP_MEMORY_SCOPE_AGENT);
      *(ull*)(buf + swzH(r, k)) = v;
    }
    __syncthreads();

    // ---- GEMM2 (2-way K-split across wave pairs), W2 from L2 ----
    ffrag accB = {0.f, 0.f, 0.f, 0.f};
#pragma unroll 8
    for (int kk = 0; kk < 32; ++kk) {
      const int k0 = (kh << 10) + (kk << 5) + (quad << 3);
      const bfrag a = *(const bfrag*)(buf + swzH(l16, k0));
      const bfrag bm = *(const bfrag*)(g_W2b + (size_t)(zc0 + l16) * HD + k0);
      accB = __builtin_amdgcn_mfma_f32_16x16x32_bf16(a, bm, accB, 0, 0, 0);
    }
    __syncthreads();  // all buf reads done
    if (kh == 1) *(ffrag*)(red + (((nq << 6) + lane) << 2)) = accB;
    __syncthreads();
    if (kh == 0) {
      accB += *(const ffrag*)(red + (((nq << 6) + lane) << 2));
      const int zc = zc0 + l16;
      const float b2v = b2[zc];
#pragma unroll
      for (int rg = 0; rg < 4; ++rg) {
        const int row = (quad << 2) + rg;
        zreg[rg] += dtv * (accB[rg] + b2v);
        out[(size_t)(r0 + row) * ZT + (size_t)zc * TT + t + 1] = zreg[rg];
        zloc[row * 68 + (nq << 4) + l16] = f2bf(zreg[rg]);
      }
    }
    __syncthreads();

    // ---- publish z(t+1) slice (16x64) as 8B chunks ----
    if (tid < 256) {
      const int row = tid >> 4, ch = (tid & 15) << 2;
      const ull v = *(const ull*)(zloc + row * 68 + ch);
      __hip_atomic_store(&g_zbx[((r0 + row) * ZD + (ng << 6) + ch) >> 2], v,
                         __ATOMIC_RELAXED, __HIP_MEMORY_SCOPE_AGENT);
    }
    __syncthreads();  // vmcnt(0): z(t+1) at coherence point
    if (tid == 0)
      __hip_atomic_store(&g_zfl[myslot], (unsigned)(t + 2), __ATOMIC_RELAXED,
                         __HIP_MEMORY_SCOPE_AGENT);
  }
}

extern "C" void kernel_launch(void* const* d_in, const int* in_sizes, int n_in,
                              void* d_out, int out_size, void* d_ws, size_t ws_size,
                              hipStream_t stream) {
  const float* z0 = (const float*)d_in[0];
  const float* ts = (const float*)d_in[1];
  const float* W1 = (const float*)d_in[2];
  const float* wt = (const float*)d_in[3];
  const float* b1 = (const float*)d_in[4];
  const float* W2 = (const float*)d_in[5];
  const float* b2 = (const float*)d_in[6];
  float* out = (float*)d_out;

  zero_flags_kernel<<<8, 1024, 0, stream>>>();
  cvt_weights_kernel<<<(HD * ZD) / 1024, 256, 0, stream>>>(W1, W2);
  ode_main<<<256, 512, 0, stream>>>(z0, ts, wt, b1, b2, out);
}